// Round 1
// baseline (214.767 us; speedup 1.0000x reference)
//
#include <hip/hip_runtime.h>

#define DIM 2048
#define NQ 11
#define NROT 88
#define BSZ 64
#define NT 8
#define NPC 4   // DEGREE+1

// ---------------------------------------------------------------------------
// Gate descriptor decode: gate j in [0,44) within a layer.
// wire w <-> flat bit p = 10 - w  (wire 0 = most significant axis)
// type 0 = RY (pt = target bit), type 1 = CRX (pcb = control bit, pt = target)
// ---------------------------------------------------------------------------
__device__ __forceinline__ void decode_gate(int j, int& type, int& pt, int& pcb) {
    if (j < 11) {                       // RY wires 0..10
        type = 0; pt = 10 - j; pcb = -1;
    } else if (j < 22) {                // CRX ctrl i, tgt (i+1)%11, i = 10..0
        int i = 21 - j;
        type = 1; pcb = 10 - i;
        int tw = (i + 1 == NQ) ? 0 : i + 1;
        pt = 10 - tw;
    } else if (j < 33) {                // RY wires 0..10
        type = 0; pt = 10 - (j - 22); pcb = -1;
    } else if (j == 33) {               // CRX ctrl 10, tgt 9
        type = 1; pcb = 0; pt = 1;
    } else {                            // CRX ctrl i, tgt (i-1)%11, i = 0..9
        int i = j - 34;
        type = 1; pcb = 10 - i;
        int tw = (i + 10) % NQ;
        pt = 10 - tw;
    }
}

// ---------------------------------------------------------------------------
// Gate kernels on LDS state (separate re/im planes). Each ends with a barrier.
// ---------------------------------------------------------------------------
__device__ __forceinline__ void gate_ry(float* sre, float* sim_, int p, float c, float s) {
    int tid = threadIdx.x;
#pragma unroll
    for (int it = 0; it < 4; ++it) {
        int k = tid + it * 256;                     // 1024 pairs
        int lo = ((k >> p) << (p + 1)) | (k & ((1 << p) - 1));
        int hi = lo | (1 << p);
        float a0r = sre[lo], a1r = sre[hi];
        float a0i = sim_[lo], a1i = sim_[hi];
        sre[lo] = c * a0r - s * a1r;
        sre[hi] = s * a0r + c * a1r;
        sim_[lo] = c * a0i - s * a1i;
        sim_[hi] = s * a0i + c * a1i;
    }
    __syncthreads();
}

__device__ __forceinline__ void gate_crx(float* sre, float* sim_, int pcb, int pt, float c, float s) {
    int tid = threadIdx.x;
    int pl = pcb < pt ? pcb : pt;
    int ph = pcb < pt ? pt : pcb;
#pragma unroll
    for (int it = 0; it < 2; ++it) {
        int k = tid + it * 256;                     // 512 pairs (control = 1)
        int x = ((k >> pl) << (pl + 1)) | (k & ((1 << pl) - 1));
        x = ((x >> ph) << (ph + 1)) | (x & ((1 << ph) - 1));
        int i0 = x | (1 << pcb);                    // target bit 0
        int i1 = i0 | (1 << pt);                    // target bit 1
        float a0r = sre[i0], a0i = sim_[i0];
        float a1r = sre[i1], a1i = sim_[i1];
        // RX: new0 = c*a0 - i*s*a1 ; new1 = c*a1 - i*s*a0
        sre[i0] = c * a0r + s * a1i;
        sim_[i0] = c * a0i - s * a1r;
        sre[i1] = c * a1r + s * a0i;
        sim_[i1] = c * a1i - s * a0r;
    }
    __syncthreads();
}

// ---------------------------------------------------------------------------
// Setup: normalize base states, init working = base, acc = pc[0]*base
// ---------------------------------------------------------------------------
__global__ __launch_bounds__(256) void setup_kernel(
    const float* __restrict__ base, const float* __restrict__ pc,
    float2* __restrict__ working, float2* __restrict__ acc)
{
    int b = blockIdx.x;
    int tid = threadIdx.x;
    __shared__ float red[4];
    float ssum = 0.f;
    for (int i = tid; i < DIM; i += 256) {
        float v = base[b * DIM + i];
        ssum += v * v;
    }
    for (int off = 32; off > 0; off >>= 1) ssum += __shfl_down(ssum, off, 64);
    if ((tid & 63) == 0) red[tid >> 6] = ssum;
    __syncthreads();
    if (tid == 0) red[0] = red[0] + red[1] + red[2] + red[3];
    __syncthreads();
    float inv = rsqrtf(red[0]);
    float p0 = pc[0];
    for (int i = tid; i < DIM; i += 256) {
        float v = base[b * DIM + i] * inv;
        working[b * DIM + i] = make_float2(v, 0.f);
        acc[b * DIM + i] = make_float2(p0 * v, 0.f);
    }
}

// ---------------------------------------------------------------------------
// Evolve: block = (b, chunk). Evolves tpb timesteps from working[b], each
// through the 88-gate circuit, accumulating coeff-weighted sum in LDS.
// Writes partial[b][chunk] = sum_{t in chunk} lcu[b,t] * U(params[b,t]) w[b]
// ---------------------------------------------------------------------------
__global__ __launch_bounds__(256) void evolve_kernel(
    const float2* __restrict__ working, const float* __restrict__ uparams,
    const float* __restrict__ lcu, float2* __restrict__ partial, int tpb)
{
    __shared__ float sre[DIM], simg[DIM];
    __shared__ float are[DIM], aim[DIM];
    __shared__ float sc[NROT], ss[NROT];

    int nchunks = NT / tpb;
    int b = blockIdx.x / nchunks;
    int chunk = blockIdx.x - b * nchunks;
    int tid = threadIdx.x;

    for (int i = tid; i < DIM; i += 256) { are[i] = 0.f; aim[i] = 0.f; }

    for (int tt = 0; tt < tpb; ++tt) {
        int t = chunk * tpb + tt;
        // per-timestep half-angle tables
        if (tid < NROT) {
            float th = 0.5f * uparams[(b * NT + t) * NROT + tid];
            sc[tid] = cosf(th);
            ss[tid] = sinf(th);
        }
        // load state
        for (int i = tid; i < DIM; i += 256) {
            float2 v = working[b * DIM + i];
            sre[i] = v.x; simg[i] = v.y;
        }
        __syncthreads();

        // 88 gates = 2 layers x 44
        int idx = 0;
        for (int layer = 0; layer < 2; ++layer) {
            for (int j = 0; j < 44; ++j) {
                int type, pt, pcb;
                decode_gate(j, type, pt, pcb);
                float c = sc[idx], s = ss[idx];
                if (type == 0) gate_ry(sre, simg, pt, c, s);
                else           gate_crx(sre, simg, pcb, pt, c, s);
                ++idx;
            }
        }

        float coeff = lcu[b * NT + t];
        for (int i = tid; i < DIM; i += 256) {
            are[i] += coeff * sre[i];
            aim[i] += coeff * simg[i];
        }
        __syncthreads();   // protect sre/simg/sc/ss before next timestep
    }

    for (int i = tid; i < DIM; i += 256)
        partial[((size_t)b * nchunks + chunk) * DIM + i] = make_float2(are[i], aim[i]);
}

// ---------------------------------------------------------------------------
// Reduce: working[b] = sum_chunk partial[b][chunk]; acc += pc[k]*working;
// on last step also write out = acc / sum(|pc|) as (re,im) pairs.
// ---------------------------------------------------------------------------
__global__ __launch_bounds__(256) void reduce_kernel(
    const float2* __restrict__ partial, const float* __restrict__ pcoef,
    float2* __restrict__ working, float2* __restrict__ acc,
    float* __restrict__ out, int nchunks, int k, int last)
{
    int b = blockIdx.x;
    int tid = threadIdx.x;
    float pk = pcoef[k];
    float invn = 0.f;
    if (last) {
        float s = 0.f;
        for (int i = 0; i < NPC; ++i) s += fabsf(pcoef[i]);
        invn = 1.0f / s;
    }
    for (int i = tid; i < DIM; i += 256) {
        float sr = 0.f, si = 0.f;
        for (int c = 0; c < nchunks; ++c) {
            float2 v = partial[((size_t)b * nchunks + c) * DIM + i];
            sr += v.x; si += v.y;
        }
        working[b * DIM + i] = make_float2(sr, si);
        float2 a = acc[b * DIM + i];
        a.x += pk * sr; a.y += pk * si;
        acc[b * DIM + i] = a;
        if (last) {
            out[((size_t)b * DIM + i) * 2 + 0] = a.x * invn;
            out[((size_t)b * DIM + i) * 2 + 1] = a.y * invn;
        }
    }
}

extern "C" void kernel_launch(void* const* d_in, const int* in_sizes, int n_in,
                              void* d_out, int out_size, void* d_ws, size_t ws_size,
                              hipStream_t stream) {
    const float* base = (const float*)d_in[0];   // (64, 2048) f32
    const float* upar = (const float*)d_in[1];   // (64, 8, 88) f32
    const float* lcu  = (const float*)d_in[2];   // (64, 8) f32
    const float* pc   = (const float*)d_in[3];   // (4,) f32
    float* out = (float*)d_out;                  // (64, 2048, 2) f32

    const size_t plane = (size_t)BSZ * DIM * sizeof(float2);   // 1 MB
    char* ws = (char*)d_ws;
    float2* working = (float2*)ws;
    float2* acc     = (float2*)(ws + plane);
    float2* partial = (float2*)(ws + 2 * plane);

    // choose timesteps-per-block so partial buffer fits in ws
    int tpb = 1;
    while (tpb < NT && 2 * plane + (size_t)(NT / tpb) * plane > ws_size) tpb <<= 1;
    int nchunks = NT / tpb;

    setup_kernel<<<BSZ, 256, 0, stream>>>(base, pc, working, acc);
    for (int k = 1; k <= NPC - 1; ++k) {
        evolve_kernel<<<BSZ * nchunks, 256, 0, stream>>>(working, upar, lcu, partial, tpb);
        reduce_kernel<<<BSZ, 256, 0, stream>>>(partial, pc, working, acc, out,
                                               nchunks, k, (k == NPC - 1) ? 1 : 0);
    }
}